// Round 4
// baseline (113.153 us; speedup 1.0000x reference)
//
#include <hip/hip_runtime.h>

// Bidirectional chamfer, B=4, N=M=5000, D=3, fp32.
// R4: wave-pair j-split. Each block owns 20 queries (2 groups of 10); within
// a group, 2 waves split the target range; lanes split targets 64-way;
// shfl_xor butterfly + one LDS min combines. Grid 2000 blocks (~8/CU).

#define BB      4
#define NP      5000
#define NPP     5120              // padded targets (sentinels)
#define THREADS 256
#define QW      10                // queries per wave-group
#define QB      (2 * QW)          // 20 queries per block
#define XBLKS   (NP / QB)         // 250
#define GRID    (XBLKS * 2 * BB)  // 2000 blocks
#define CN      1024              // targets per LDS chunk (16 KB float4)
#define NCHUNK  (NPP / CN)        // 5
#define KH      8                 // k-slots per wave (16 per chunk, split 2-way)
#define BIGF    3.0e38f

// packed[src*4 + b][j] = (x, y, z, |p|^2), sentinel (0,0,0,BIGF) for j>=NP
__global__ __launch_bounds__(256) void dl_prep_kernel(
    const float* __restrict__ pred, const float* __restrict__ gt,
    float4* __restrict__ packed, unsigned* __restrict__ counter) {
    const int idx = blockIdx.x * 256 + threadIdx.x;
    if (idx == 0) counter[0] = 0u;
    if (idx >= 8 * NPP) return;
    const int j  = idx % NPP;
    const int sb = idx / NPP;   // s*4 + b
    const int b  = sb & 3;
    const float* src = (sb >> 2) ? gt : pred;
    float4 v = make_float4(0.f, 0.f, 0.f, BIGF);
    if (j < NP) {
        const float* p = src + ((size_t)b * NP + j) * 3;
        const float x = p[0], y = p[1], z = p[2];
        v = make_float4(x, y, z, x * x + y * y + z * z);
    }
    packed[idx] = v;
}

__global__ __launch_bounds__(THREADS, 6) void dl_chamfer_kernel(
    const float4* __restrict__ packed,
    float* __restrict__ partials,      // [GRID]
    unsigned* __restrict__ counter,
    float* __restrict__ out) {
    const int qblk = blockIdx.x;            // 0..249
    const int bz   = blockIdx.y;            // 0..7
    const int b    = bz >> 1;
    const int dir  = bz & 1;
    const float4* qpk = packed + ((size_t)(dir * 4 + b)) * NPP;
    const float4* tpk = packed + ((size_t)((1 - dir) * 4 + b)) * NPP;

    const int lane = threadIdx.x & 63;
    const int wave = __builtin_amdgcn_readfirstlane(threadIdx.x >> 6);
    const int pair = wave >> 1;             // query group 0/1
    const int jh   = wave & 1;              // which half of each chunk

    // ---- this wave's 10 queries (wave-uniform), from packed (q2 = .w free)
    float qsx[QW], qsy[QW], qsz[QW], q2[QW], m[QW];
    const int qbase = qblk * QB + pair * QW;
    #pragma unroll
    for (int r = 0; r < QW; ++r) {
        const float4 qv = qpk[qbase + r];
        qsx[r] = -2.0f * qv.x; qsy[r] = -2.0f * qv.y; qsz[r] = -2.0f * qv.z;
        q2[r] = qv.w; m[r] = BIGF;
    }

    // ---- stage chunks; each wave reads only its half (jh)
    __shared__ float4 tg[CN];
    for (int c = 0; c < NCHUNK; ++c) {
        __syncthreads();                       // prior readers done (WAR)
        #pragma unroll
        for (int i = 0; i < CN / THREADS; ++i) {
            const int e = i * THREADS + threadIdx.x;
            tg[e] = tpk[c * CN + e];           // dwordx4 -> ds_write_b128
        }
        __syncthreads();

        #pragma unroll 4
        for (int k = 0; k < KH; ++k) {
            const float4 g = tg[(jh * KH + k) * 64 + lane];  // conflict-free
            #pragma unroll
            for (int r = 0; r < QW; ++r) {
                // |g|^2 - 2 q.g : 3 fma + min per pair
                float d = __builtin_fmaf(qsz[r], g.z, g.w);
                d = __builtin_fmaf(qsy[r], g.y, d);
                d = __builtin_fmaf(qsx[r], g.x, d);
                m[r] = fminf(m[r], d);
            }
        }
    }

    // ---- cross-lane min butterfly (lanes covered disjoint targets)
    #pragma unroll
    for (int r = 0; r < QW; ++r) {
        float v = m[r];
        #pragma unroll
        for (int off = 1; off < 64; off <<= 1)
            v = fminf(v, __shfl_xor(v, off, 64));
        m[r] = v;
    }

    // ---- cross-wave (pair) min + row sums
    __shared__ float mshare[4][QW];
    __shared__ float wsum[2];
    if (lane == 0) {
        #pragma unroll
        for (int r = 0; r < QW; ++r) mshare[wave][r] = m[r];
    }
    __syncthreads();
    if ((wave & 1) == 0 && lane == 0) {
        float s = 0.0f;
        #pragma unroll
        for (int r = 0; r < QW; ++r)
            s += fmaxf(q2[r] + fminf(m[r], mshare[wave + 1][r]), 0.0f);
        wsum[pair] = s;
    }
    __syncthreads();

    const int bid = blockIdx.y * XBLKS + blockIdx.x;
    __shared__ unsigned lastFlag;
    if (threadIdx.x == 0) {
        partials[bid] = wsum[0] + wsum[1];
        __threadfence();
        lastFlag = (atomicAdd(counter, 1u) == GRID - 1) ? 1u : 0u;
    }
    __syncthreads();

    // ---- last-block finalize: sum 2000 partials
    if (lastFlag) {
        __threadfence();
        float s = 0.0f;
        for (int i = threadIdx.x; i < GRID; i += THREADS)
            s += __hip_atomic_load((const float*)partials + i, __ATOMIC_RELAXED,
                                   __HIP_MEMORY_SCOPE_AGENT);
        #pragma unroll
        for (int off = 32; off > 0; off >>= 1)
            s += __shfl_down(s, off, 64);
        __shared__ float fsum[4];
        if (lane == 0) fsum[wave] = s;
        __syncthreads();
        if (threadIdx.x == 0)
            out[0] = (fsum[0] + fsum[1] + fsum[2] + fsum[3]) / (float)(BB * NP);
    }
}

extern "C" void kernel_launch(void* const* d_in, const int* in_sizes, int n_in,
                              void* d_out, int out_size, void* d_ws, size_t ws_size,
                              hipStream_t stream) {
    const float* pred = (const float*)d_in[0];
    const float* gt   = (const float*)d_in[1];
    float4* packed    = (float4*)d_ws;                   // 8*5120*16 B = 640 KB
    float* partials   = (float*)d_ws + 8 * NPP * 4;      // 2000 floats
    unsigned* counter = (unsigned*)(partials + GRID);    // 1 u32
    float* out        = (float*)d_out;

    dl_prep_kernel<<<dim3((8 * NPP + 255) / 256), 256, 0, stream>>>(
        pred, gt, packed, counter);
    dl_chamfer_kernel<<<dim3(XBLKS, 2 * BB), THREADS, 0, stream>>>(
        packed, partials, counter, out);
}

// Round 5
// 112.994 us; speedup vs baseline: 1.0014x; 1.0014x over previous
//
#include <hip/hip_runtime.h>

// Bidirectional chamfer, B=4, N=M=5000, D=3, fp32.
// R5 = R4 structure (wave-pair j-split, 2000 blocks) minus the VGPR spill:
// no min-waves clamp in launch_bounds, and q2 recomputed from -2q after the
// loop instead of being kept live across it.

#define BB      4
#define NP      5000
#define NPP     5120              // padded targets (sentinels)
#define THREADS 256
#define QW      10                // queries per wave-group
#define QB      (2 * QW)          // 20 queries per block
#define XBLKS   (NP / QB)         // 250
#define GRID    (XBLKS * 2 * BB)  // 2000 blocks ~= 8 per CU
#define CN      1024              // targets per LDS chunk (16 KB float4)
#define NCHUNK  (NPP / CN)        // 5
#define KH      8                 // k-slots per wave (16 per chunk, split 2-way)
#define BIGF    3.0e38f

// packed[src*4 + b][j] = (x, y, z, |p|^2), sentinel (0,0,0,BIGF) for j>=NP
__global__ __launch_bounds__(256) void dl_prep_kernel(
    const float* __restrict__ pred, const float* __restrict__ gt,
    float4* __restrict__ packed, unsigned* __restrict__ counter) {
    const int idx = blockIdx.x * 256 + threadIdx.x;
    if (idx == 0) counter[0] = 0u;
    if (idx >= 8 * NPP) return;
    const int j  = idx % NPP;
    const int sb = idx / NPP;   // s*4 + b
    const int b  = sb & 3;
    const float* src = (sb >> 2) ? gt : pred;
    float4 v = make_float4(0.f, 0.f, 0.f, BIGF);
    if (j < NP) {
        const float* p = src + ((size_t)b * NP + j) * 3;
        const float x = p[0], y = p[1], z = p[2];
        v = make_float4(x, y, z, x * x + y * y + z * z);
    }
    packed[idx] = v;
}

__global__ __launch_bounds__(THREADS) void dl_chamfer_kernel(
    const float4* __restrict__ packed,
    float* __restrict__ partials,      // [GRID]
    unsigned* __restrict__ counter,
    float* __restrict__ out) {
    const int qblk = blockIdx.x;            // 0..249
    const int bz   = blockIdx.y;            // 0..7
    const int b    = bz >> 1;
    const int dir  = bz & 1;
    const float4* qpk = packed + ((size_t)(dir * 4 + b)) * NPP;
    const float4* tpk = packed + ((size_t)((1 - dir) * 4 + b)) * NPP;

    const int lane = threadIdx.x & 63;
    const int wave = __builtin_amdgcn_readfirstlane(threadIdx.x >> 6);
    const int pair = wave >> 1;             // query group 0/1
    const int jh   = wave & 1;              // which half of each chunk

    // ---- this wave's 10 queries (wave-uniform); only -2q and m stay live
    float qsx[QW], qsy[QW], qsz[QW], m[QW];
    const int qbase = qblk * QB + pair * QW;
    #pragma unroll
    for (int r = 0; r < QW; ++r) {
        const float4 qv = qpk[qbase + r];
        qsx[r] = -2.0f * qv.x; qsy[r] = -2.0f * qv.y; qsz[r] = -2.0f * qv.z;
        m[r] = BIGF;
    }

    // ---- stage chunks; each wave reads only its half (jh)
    __shared__ float4 tg[CN];
    for (int c = 0; c < NCHUNK; ++c) {
        __syncthreads();                       // prior readers done (WAR)
        #pragma unroll
        for (int i = 0; i < CN / THREADS; ++i) {
            const int e = i * THREADS + threadIdx.x;
            tg[e] = tpk[c * CN + e];           // dwordx4 -> ds_write_b128
        }
        __syncthreads();

        #pragma unroll 4
        for (int k = 0; k < KH; ++k) {
            const float4 g = tg[(jh * KH + k) * 64 + lane];  // conflict-free
            #pragma unroll
            for (int r = 0; r < QW; ++r) {
                // |g|^2 - 2 q.g : 3 fma + min per pair
                float d = __builtin_fmaf(qsz[r], g.z, g.w);
                d = __builtin_fmaf(qsy[r], g.y, d);
                d = __builtin_fmaf(qsx[r], g.x, d);
                m[r] = fminf(m[r], d);
            }
        }
    }

    // ---- cross-lane min butterfly (lanes covered disjoint targets)
    #pragma unroll
    for (int r = 0; r < QW; ++r) {
        float v = m[r];
        #pragma unroll
        for (int off = 1; off < 64; off <<= 1)
            v = fminf(v, __shfl_xor(v, off, 64));
        m[r] = v;
    }

    // ---- cross-wave (pair) min + row sums; q2 recomputed from -2q here
    __shared__ float mshare[4][QW];
    __shared__ float wsum[2];
    if (lane == 0) {
        #pragma unroll
        for (int r = 0; r < QW; ++r) mshare[wave][r] = m[r];
    }
    __syncthreads();
    if ((wave & 1) == 0 && lane == 0) {
        float s = 0.0f;
        #pragma unroll
        for (int r = 0; r < QW; ++r) {
            const float q2 = 0.25f * (qsx[r] * qsx[r] + qsy[r] * qsy[r] +
                                      qsz[r] * qsz[r]);
            s += fmaxf(q2 + fminf(m[r], mshare[wave + 1][r]), 0.0f);
        }
        wsum[pair] = s;
    }
    __syncthreads();

    const int bid = blockIdx.y * XBLKS + blockIdx.x;
    __shared__ unsigned lastFlag;
    if (threadIdx.x == 0) {
        partials[bid] = wsum[0] + wsum[1];
        __threadfence();
        lastFlag = (atomicAdd(counter, 1u) == GRID - 1) ? 1u : 0u;
    }
    __syncthreads();

    // ---- last-block finalize: sum 2000 partials
    if (lastFlag) {
        __threadfence();
        float s = 0.0f;
        for (int i = threadIdx.x; i < GRID; i += THREADS)
            s += __hip_atomic_load((const float*)partials + i, __ATOMIC_RELAXED,
                                   __HIP_MEMORY_SCOPE_AGENT);
        #pragma unroll
        for (int off = 32; off > 0; off >>= 1)
            s += __shfl_down(s, off, 64);
        __shared__ float fsum[4];
        if (lane == 0) fsum[wave] = s;
        __syncthreads();
        if (threadIdx.x == 0)
            out[0] = (fsum[0] + fsum[1] + fsum[2] + fsum[3]) / (float)(BB * NP);
    }
}

extern "C" void kernel_launch(void* const* d_in, const int* in_sizes, int n_in,
                              void* d_out, int out_size, void* d_ws, size_t ws_size,
                              hipStream_t stream) {
    const float* pred = (const float*)d_in[0];
    const float* gt   = (const float*)d_in[1];
    float4* packed    = (float4*)d_ws;                   // 8*5120*16 B = 640 KB
    float* partials   = (float*)d_ws + 8 * NPP * 4;      // 2000 floats
    unsigned* counter = (unsigned*)(partials + GRID);    // 1 u32
    float* out        = (float*)d_out;

    dl_prep_kernel<<<dim3((8 * NPP + 255) / 256), 256, 0, stream>>>(
        pred, gt, packed, counter);
    dl_chamfer_kernel<<<dim3(XBLKS, 2 * BB), THREADS, 0, stream>>>(
        packed, partials, counter, out);
}

// Round 6
// 82.596 us; speedup vs baseline: 1.3700x; 1.3680x over previous
//
#include <hip/hip_runtime.h>

// Bidirectional chamfer, B=4, N=M=5000, D=3, fp32.
// R6: single-stage LDS. All 5120 padded targets (float4 incl |g|^2, 80 KB)
// staged ONCE into LDS by a 1024-thread block; ONE barrier; then the entire
// 80-iteration k-loop runs with zero barriers and zero global loads.
// 256 blocks (1/CU), 16 waves/block, 10 queries/wave, lanes split targets.

#define BB      4
#define NP      5000
#define NPP     5120               // padded targets (sentinels w=BIGF)
#define THREADS 1024
#define WAVES   16
#define QW      10                 // queries per wave
#define QPB     (WAVES * QW)       // 160 queries per block
#define XBLKS   32                 // 32*160 = 5120 >= 5000 (masked tail)
#define GRID    (XBLKS * 2 * BB)   // 256 blocks = 1 per CU
#define KITER   (NPP / 64)         // 80 j's per lane
#define BIGF    3.0e38f

// packed[src*4 + b][j] = (x, y, z, |p|^2); sentinel (0,0,0,BIGF) for j>=NP
__global__ __launch_bounds__(256) void dl_prep_kernel(
    const float* __restrict__ pred, const float* __restrict__ gt,
    float4* __restrict__ packed, unsigned* __restrict__ counter) {
    const int idx = blockIdx.x * 256 + threadIdx.x;
    if (idx == 0) counter[0] = 0u;
    if (idx >= 8 * NPP) return;
    const int j  = idx % NPP;
    const int sb = idx / NPP;   // s*4 + b
    const int b  = sb & 3;
    const float* src = (sb >> 2) ? gt : pred;
    float4 v = make_float4(0.f, 0.f, 0.f, BIGF);
    if (j < NP) {
        const float* p = src + ((size_t)b * NP + j) * 3;
        const float x = p[0], y = p[1], z = p[2];
        v = make_float4(x, y, z, x * x + y * y + z * z);
    }
    packed[idx] = v;
}

__global__ __launch_bounds__(THREADS) void dl_chamfer_kernel(
    const float4* __restrict__ packed,
    float* __restrict__ partials,      // [GRID]
    unsigned* __restrict__ counter,
    float* __restrict__ out) {
    const int qblk = blockIdx.x;            // 0..31
    const int bz   = blockIdx.y;            // 0..7
    const int b    = bz >> 1;
    const int dir  = bz & 1;
    const float4* qpk = packed + ((size_t)(dir * 4 + b)) * NPP;
    const float4* tpk = packed + ((size_t)((1 - dir) * 4 + b)) * NPP;

    const int lane = threadIdx.x & 63;
    const int wave = __builtin_amdgcn_readfirstlane(threadIdx.x >> 6);

    // ---- stage ALL targets once: 80 KB LDS, 5 coalesced dwordx4 per thread
    __shared__ float4 tg[NPP];
    #pragma unroll
    for (int i = 0; i < NPP / THREADS; ++i) {
        const int e = i * THREADS + threadIdx.x;
        tg[e] = tpk[e];
    }

    // ---- this wave's 10 queries (wave-uniform addresses)
    float qsx[QW], qsy[QW], qsz[QW], q2[QW], m[QW];
    const int qbase = qblk * QPB + wave * QW;
    #pragma unroll
    for (int r = 0; r < QW; ++r) {
        const float4 qv = qpk[qbase + r];
        qsx[r] = -2.0f * qv.x; qsy[r] = -2.0f * qv.y; qsz[r] = -2.0f * qv.z;
        q2[r] = qv.w; m[r] = BIGF;
    }

    __syncthreads();   // the ONLY staging barrier

    // ---- barrier-free main loop: 80 conflict-free ds_read_b128 per lane
    #pragma unroll 4
    for (int k = 0; k < KITER; ++k) {
        const float4 g = tg[k * 64 + lane];
        #pragma unroll
        for (int r = 0; r < QW; ++r) {
            // |g|^2 - 2 q.g : 3 fma + min per pair
            float d = __builtin_fmaf(qsz[r], g.z, g.w);
            d = __builtin_fmaf(qsy[r], g.y, d);
            d = __builtin_fmaf(qsx[r], g.x, d);
            m[r] = fminf(m[r], d);
        }
    }

    // ---- cross-lane min butterfly (lanes covered disjoint targets)
    #pragma unroll
    for (int r = 0; r < QW; ++r) {
        float v = m[r];
        #pragma unroll
        for (int off = 1; off < 64; off <<= 1)
            v = fminf(v, __shfl_xor(v, off, 64));
        m[r] = v;
    }

    // ---- per-wave row sums (mask padded queries), then block sum
    __shared__ float wsum[WAVES];
    if (lane == 0) {
        float s = 0.0f;
        #pragma unroll
        for (int r = 0; r < QW; ++r) {
            const float c = fmaxf(q2[r] + m[r], 0.0f);
            s += (qbase + r < NP) ? c : 0.0f;
        }
        wsum[wave] = s;
    }
    __syncthreads();

    const int bid = blockIdx.y * XBLKS + blockIdx.x;
    __shared__ unsigned lastFlag;
    if (threadIdx.x == 0) {
        float s = 0.0f;
        #pragma unroll
        for (int w = 0; w < WAVES; ++w) s += wsum[w];
        partials[bid] = s;
        __threadfence();
        lastFlag = (atomicAdd(counter, 1u) == GRID - 1) ? 1u : 0u;
    }
    __syncthreads();

    // ---- last-block finalize: sum 256 partials
    if (lastFlag) {
        __threadfence();
        float s = 0.0f;
        for (int i = threadIdx.x; i < GRID; i += THREADS)
            s += __hip_atomic_load((const float*)partials + i, __ATOMIC_RELAXED,
                                   __HIP_MEMORY_SCOPE_AGENT);
        #pragma unroll
        for (int off = 32; off > 0; off >>= 1)
            s += __shfl_down(s, off, 64);
        if (lane == 0) wsum[wave] = s;   // reuse wsum
        __syncthreads();
        if (threadIdx.x == 0) {
            float t = 0.0f;
            #pragma unroll
            for (int w = 0; w < WAVES; ++w) t += wsum[w];
            out[0] = t / (float)(BB * NP);
        }
    }
}

extern "C" void kernel_launch(void* const* d_in, const int* in_sizes, int n_in,
                              void* d_out, int out_size, void* d_ws, size_t ws_size,
                              hipStream_t stream) {
    const float* pred = (const float*)d_in[0];
    const float* gt   = (const float*)d_in[1];
    float4* packed    = (float4*)d_ws;                   // 8*5120*16 B = 640 KB
    float* partials   = (float*)d_ws + 8 * NPP * 4;      // 256 floats
    unsigned* counter = (unsigned*)(partials + GRID);    // 1 u32
    float* out        = (float*)d_out;

    dl_prep_kernel<<<dim3((8 * NPP + 255) / 256), 256, 0, stream>>>(
        pred, gt, packed, counter);
    dl_chamfer_kernel<<<dim3(XBLKS, 2 * BB), THREADS, 0, stream>>>(
        packed, partials, counter, out);
}